// Round 1
// baseline (146.651 us; speedup 1.0000x reference)
//
#include <hip/hip_runtime.h>
#include <stdint.h>

// KANLinear fused MFMA GEMM, R6: 128x256 tile (full output width per block)
//   - A-expansion (silu | bspline) computed ONCE per row (was 2x: col-split grid)
//   - full-range basis table: u in [0,11) x 512 bins -> 16B row with the 4
//     nonzero cubic-spline bf16 coefs PRE-POSITIONED (kills the __int128 shift)
//   - 1024 threads / 16 waves (4 per SIMD), BK=64 double-buffered, 96 KB LDS
//   C = A @ W^T, A (B x 2304) = [silu(x) | bases(x)], W (256 x 2304) bf16 in ws.

#define IN_F 256
#define OUT_F 256
#define KDIM 2304 /* 256 silu + 256*8 basis */
#define BK 64
#define NCHUNK (KDIM / BK) /* 36 */
#define TBINS 512
#define NTAB (11 * TBINS)     /* 5632 real entries (j0 0..10 x 512 bins) */
#define NTAB_PAD (NTAB + 2)   /* zero guard rows at both ends */
#define WC_BYTES ((size_t)OUT_F * KDIM * 2) /* 1,179,648 (16-aligned) */

#define AS1 __attribute__((address_space(1)))
#define AS3 __attribute__((address_space(3)))

typedef float f32x4 __attribute__((ext_vector_type(4)));
typedef short bf16x8 __attribute__((ext_vector_type(8)));

__device__ __forceinline__ uint32_t f2bf(float f) {
    union { float f; uint32_t u; } c; c.f = f;
    uint32_t u = c.u;
    return (u + 0x7FFFu + ((u >> 16) & 1u)) >> 16;   // RNE
}

__device__ __forceinline__ float silu_f(float v) {
    return v / (1.0f + __expf(-v));
}

// ---------------- kernel 1: bf16 weight + full-range basis table ----------------
__global__ void build_w(const float* __restrict__ bw, const float* __restrict__ sw,
                        const float* __restrict__ ss, unsigned short* __restrict__ Wc,
                        uint4* __restrict__ tgt) {
    const int o = blockIdx.x;
    const int i = threadIdx.x;
    Wc[o * KDIM + i] = (unsigned short)f2bf(bw[o * IN_F + i]);
    const float scal = ss[o * IN_F + i];
    const float4* swv = reinterpret_cast<const float4*>(sw + (size_t)(o * IN_F + i) * 8);
    float4 s0 = swv[0], s1 = swv[1];
    uint4 wv;
    wv.x = f2bf(s0.x * scal) | (f2bf(s0.y * scal) << 16);
    wv.y = f2bf(s0.z * scal) | (f2bf(s0.w * scal) << 16);
    wv.z = f2bf(s1.x * scal) | (f2bf(s1.y * scal) << 16);
    wv.w = f2bf(s1.z * scal) | (f2bf(s1.w * scal) << 16);
    *reinterpret_cast<uint4*>(Wc + o * KDIM + IN_F + i * 8) = wv;

    if (o == 0) {
        // entry e=0 and e=NTAB+1 are zero rows (out-of-grid clamp targets).
        // entry e=idx+1, idx = j0*512+bin: 8 bf16 coef slots, p[m] at slot j0-3+m.
        for (int e = i; e < NTAB_PAD; e += IN_F) {
            uint32_t h[4] = {0u, 0u, 0u, 0u};
            if (e >= 1 && e <= NTAB) {
                const int idx = e - 1;
                const int j0 = idx >> 9;
                const float t = ((idx & (TBINS - 1)) + 0.5f) * (1.0f / TBINS);
                const float t2 = t * t, t3 = t2 * t;
                float p[4];
                p[3] = t3 * (1.0f / 6.0f);
                p[2] = -0.5f * t3 + 0.5f * t2 + 0.5f * t + (1.0f / 6.0f);
                p[1] = 0.5f * t3 - t2 + (2.0f / 3.0f);
                const float omt = 1.0f - t;
                p[0] = omt * omt * omt * (1.0f / 6.0f);
#pragma unroll
                for (int m = 0; m < 4; ++m) {
                    int c = j0 - 3 + m;
                    if (c >= 0 && c < 8) h[c >> 1] |= f2bf(p[m]) << ((c & 1) * 16);
                }
            }
            uint4 e4; e4.x = h[0]; e4.y = h[1]; e4.z = h[2]; e4.w = h[3];
            tgt[e] = e4;
        }
    }
}

// ---------------- kernel 2: fused pipelined GEMM, 1024 threads ----------------
// LDS layout per tile: addr(row, g) = row*128B + ((g ^ (row&7))*16B), g = k/8
__launch_bounds__(1024, 4)
__global__ void kan_fused(const float* __restrict__ x, const unsigned short* __restrict__ Wc,
                          const uint4* __restrict__ tgt, float* __restrict__ out) {
    extern __shared__ __align__(16) unsigned short smem[];
    unsigned short* const Asb = smem;                  // [2][128*64]  32 KB
    unsigned short* const Bsb = smem + 2 * 128 * 64;   // [2][256*64]  64 KB

    const int bid = blockIdx.x;
    const int row0 = bid * 128;
    const int tid = threadIdx.x;
    const int lane = tid & 63;
    const int w = tid >> 6;            // wave id 0..15
    const int wm = w >> 2;             // 0..3 : 32-row quarter
    const int wn = w & 3;              // 0..3 : 64-col quarter
    const int l15 = lane & 15;
    const int q = lane >> 4;

    // staging mapping (per thread, per chunk):
    //   A: 1 segment  (row arow, logical k-seg g)   B: 2 segments
    const int sr = lane >> 3;          // row within 8-row group
    const int s  = lane & 7;           // physical 16B segment
    const int g  = s ^ sr;             // logical k-segment held by this thread
    const int arow = w * 8 + sr;       // A stage row 0..127
    const int brow = w * 16 + sr;      // B stage row base (+ j*8)

    f32x4 acc[2][4] = {};
    float xr[8];                       // staged x (silu chunks)
    uint4 pk;                          // gathered full-row table entry (basis chunks)

    auto stage_b = [&](int kc, int buf) {
#pragma unroll
        for (int j = 0; j < 2; ++j) {
            const unsigned short* gp =
                Wc + (size_t)(brow + j * 8) * KDIM + kc * BK + g * 8;
            __builtin_amdgcn_global_load_lds((const AS1 void*)gp,
                (AS3 void*)(Bsb + buf * (256 * 64) + (w * 16 + j * 8) * 64), 16, 0, 0);
        }
    };
    auto load_x = [&](int kc) {
        if (kc < 4) {
            const float* xp = x + (size_t)(row0 + arow) * IN_F + kc * 64 + g * 8;
            float4 a = *reinterpret_cast<const float4*>(xp);
            float4 b = *reinterpret_cast<const float4*>(xp + 4);
            xr[0] = a.x; xr[1] = a.y; xr[2] = a.z; xr[3] = a.w;
            xr[4] = b.x; xr[5] = b.y; xr[6] = b.z; xr[7] = b.w;
        } else {
            // basis region: one (row, input) pair; dependent table gather issued
            // now so it hides under the MFMA block
            const int i0 = (kc - 4) * 8 + g;
            float xx = x[(size_t)(row0 + arow) * IN_F + i0];
            float u = __builtin_fmaf(xx, 2.5f, 5.5f);   // (x - grid0)/h
            int ic = (int)floorf(u * (float)TBINS);
            ic = ic < -1 ? -1 : (ic > NTAB ? NTAB : ic); // guards are zero rows
            pk = tgt[ic + 1];
        }
    };
    auto write_a = [&](int kc, int buf) {
        uint4 wv;
        if (kc < 4) {
            wv.x = f2bf(silu_f(xr[0])) | (f2bf(silu_f(xr[1])) << 16);
            wv.y = f2bf(silu_f(xr[2])) | (f2bf(silu_f(xr[3])) << 16);
            wv.z = f2bf(silu_f(xr[4])) | (f2bf(silu_f(xr[5])) << 16);
            wv.w = f2bf(silu_f(xr[6])) | (f2bf(silu_f(xr[7])) << 16);
        } else {
            wv = pk;                   // table row is already positioned bf16x8
        }
        *reinterpret_cast<uint4*>(Asb + buf * (128 * 64) + arow * 64 + s * 8) = wv;
    };

    // prologue: stage chunk 0 into buffer 0
    stage_b(0, 0);
    load_x(0);
    write_a(0, 0);
    __syncthreads();

    for (int kc = 0; kc < NCHUNK; ++kc) {
        const int cur = kc & 1;
        const int nxt = cur ^ 1;
        if (kc + 1 < NCHUNK) {
            stage_b(kc + 1, nxt);   // async DMA, drains at the barrier
            load_x(kc + 1);         // x loads + table gathers hide under MFMA
        }
        const unsigned short* Ac = Asb + cur * (128 * 64);
        const unsigned short* Bc = Bsb + cur * (256 * 64);
#pragma unroll
        for (int kk = 0; kk < BK; kk += 32) {
            bf16x8 af[2], bfv[4];
            const int g0 = (kk >> 3) + q;
#pragma unroll
            for (int mt = 0; mt < 2; ++mt) {
                int r = wm * 32 + mt * 16 + l15;
                af[mt] = *reinterpret_cast<const bf16x8*>(
                    Ac + r * 64 + ((g0 ^ (r & 7)) << 3));
            }
#pragma unroll
            for (int nt = 0; nt < 4; ++nt) {
                int r = wn * 64 + nt * 16 + l15;
                bfv[nt] = *reinterpret_cast<const bf16x8*>(
                    Bc + r * 64 + ((g0 ^ (r & 7)) << 3));
            }
#pragma unroll
            for (int mt = 0; mt < 2; ++mt)
#pragma unroll
                for (int nt = 0; nt < 4; ++nt)
                    acc[mt][nt] = __builtin_amdgcn_mfma_f32_16x16x32_bf16(
                        af[mt], bfv[nt], acc[mt][nt], 0, 0, 0);
        }
        if (kc + 1 < NCHUNK) write_a(kc + 1, nxt);
        __syncthreads();
    }

    // epilogue: C/D layout col = lane&15, row = (lane>>4)*4 + reg
#pragma unroll
    for (int mt = 0; mt < 2; ++mt) {
        int row = row0 + wm * 32 + mt * 16 + q * 4;
#pragma unroll
        for (int nt = 0; nt < 4; ++nt) {
            int col = wn * 64 + nt * 16 + l15;
#pragma unroll
            for (int r = 0; r < 4; ++r)
                out[(size_t)(row + r) * OUT_F + col] = acc[mt][nt][r];
        }
    }
}

extern "C" void kernel_launch(void* const* d_in, const int* in_sizes, int n_in,
                              void* d_out, int out_size, void* d_ws, size_t ws_size,
                              hipStream_t stream) {
    const float* x  = (const float*)d_in[0];
    const float* bw = (const float*)d_in[1];
    const float* sw = (const float*)d_in[2];
    const float* ss = (const float*)d_in[3];
    unsigned short* Wc = (unsigned short*)d_ws;                 // 1.18 MB
    uint4* tgt = (uint4*)((char*)d_ws + WC_BYTES);              // 90 KB table

    static bool attr_set = false;
    if (!attr_set) {
        (void)hipFuncSetAttribute(reinterpret_cast<const void*>(kan_fused),
                                  hipFuncAttributeMaxDynamicSharedMemorySize,
                                  96 * 1024);
        attr_set = true;
    }

    build_w<<<dim3(OUT_F), dim3(IN_F), 0, stream>>>(bw, sw, ss, Wc, tgt);

    const int B_ROWS = in_sizes[0] / IN_F;                      // 32768
    kan_fused<<<dim3(B_ROWS / 128), dim3(1024), 96 * 1024, stream>>>(
        x, Wc, tgt, (float*)d_out);
}

// Round 2
// 145.452 us; speedup vs baseline: 1.0082x; 1.0082x over previous
//
#include <hip/hip_runtime.h>
#include <stdint.h>

// KANLinear fused MFMA GEMM, R7: 64x256 tile, 2 blocks/CU co-residency.
//   - grid 512, 512 threads (8 waves), LDS 80 KB (As dbuf 16K + Bs dbuf 64K)
//     -> 2 independent barrier domains per CU fill each other's stalls
//   - A-expansion register pipeline deepened to 2 chunks ahead (parity sets)
//   - s_setprio(1) around MFMA cluster (block role-diversity exists now)
//   C = A @ W^T, A (B x 2304) = [silu(x) | bases(x)], W (256 x 2304) bf16 in ws.

#define IN_F 256
#define OUT_F 256
#define KDIM 2304 /* 256 silu + 256*8 basis */
#define BK 64
#define NCHUNK (KDIM / BK) /* 36, even */
#define TBINS 512
#define NTAB (11 * TBINS)     /* 5632 real entries (j0 0..10 x 512 bins) */
#define NTAB_PAD (NTAB + 2)   /* zero guard rows at both ends */
#define WC_BYTES ((size_t)OUT_F * KDIM * 2) /* 1,179,648 (16-aligned) */
#define LDS_BYTES (80 * 1024)

#define AS1 __attribute__((address_space(1)))
#define AS3 __attribute__((address_space(3)))

typedef float f32x4 __attribute__((ext_vector_type(4)));
typedef short bf16x8 __attribute__((ext_vector_type(8)));

__device__ __forceinline__ uint32_t f2bf(float f) {
    union { float f; uint32_t u; } c; c.f = f;
    uint32_t u = c.u;
    return (u + 0x7FFFu + ((u >> 16) & 1u)) >> 16;   // RNE
}

__device__ __forceinline__ float silu_f(float v) {
    return v / (1.0f + __expf(-v));
}

// ---------------- kernel 1: bf16 weight + full-range basis table ----------------
__global__ void build_w(const float* __restrict__ bw, const float* __restrict__ sw,
                        const float* __restrict__ ss, unsigned short* __restrict__ Wc,
                        uint4* __restrict__ tgt) {
    const int o = blockIdx.x;
    const int i = threadIdx.x;
    Wc[o * KDIM + i] = (unsigned short)f2bf(bw[o * IN_F + i]);
    const float scal = ss[o * IN_F + i];
    const float4* swv = reinterpret_cast<const float4*>(sw + (size_t)(o * IN_F + i) * 8);
    float4 s0 = swv[0], s1 = swv[1];
    uint4 wv;
    wv.x = f2bf(s0.x * scal) | (f2bf(s0.y * scal) << 16);
    wv.y = f2bf(s0.z * scal) | (f2bf(s0.w * scal) << 16);
    wv.z = f2bf(s1.x * scal) | (f2bf(s1.y * scal) << 16);
    wv.w = f2bf(s1.z * scal) | (f2bf(s1.w * scal) << 16);
    *reinterpret_cast<uint4*>(Wc + o * KDIM + IN_F + i * 8) = wv;

    if (o == 0) {
        // entry e=0 and e=NTAB+1 are zero rows (out-of-grid clamp targets).
        // entry e=idx+1, idx = j0*512+bin: 8 bf16 coef slots, p[m] at slot j0-3+m.
        for (int e = i; e < NTAB_PAD; e += IN_F) {
            uint32_t h[4] = {0u, 0u, 0u, 0u};
            if (e >= 1 && e <= NTAB) {
                const int idx = e - 1;
                const int j0 = idx >> 9;
                const float t = ((idx & (TBINS - 1)) + 0.5f) * (1.0f / TBINS);
                const float t2 = t * t, t3 = t2 * t;
                float p[4];
                p[3] = t3 * (1.0f / 6.0f);
                p[2] = -0.5f * t3 + 0.5f * t2 + 0.5f * t + (1.0f / 6.0f);
                p[1] = 0.5f * t3 - t2 + (2.0f / 3.0f);
                const float omt = 1.0f - t;
                p[0] = omt * omt * omt * (1.0f / 6.0f);
#pragma unroll
                for (int m = 0; m < 4; ++m) {
                    int c = j0 - 3 + m;
                    if (c >= 0 && c < 8) h[c >> 1] |= f2bf(p[m]) << ((c & 1) * 16);
                }
            }
            uint4 e4; e4.x = h[0]; e4.y = h[1]; e4.z = h[2]; e4.w = h[3];
            tgt[e] = e4;
        }
    }
}

// ---------------- kernel 2: fused pipelined GEMM, 512 threads ----------------
// LDS layout per tile: addr(row, g) = row*128B + ((g ^ (row&7))*16B), g = k/8
__launch_bounds__(512, 4)
__global__ void kan_fused(const float* __restrict__ x, const unsigned short* __restrict__ Wc,
                          const uint4* __restrict__ tgt, float* __restrict__ out) {
    extern __shared__ __align__(16) unsigned short smem[];
    unsigned short* const Asb = smem;                 // [2][64*64]   16 KB
    unsigned short* const Bsb = smem + 2 * 64 * 64;   // [2][256*64]  64 KB

    const int bid = blockIdx.x;
    const int row0 = bid * 64;
    const int tid = threadIdx.x;
    const int lane = tid & 63;
    const int w = tid >> 6;            // wave id 0..7
    const int wm = w >> 2;             // 0..1 : 32-row half
    const int wn = w & 3;              // 0..3 : 64-col quarter
    const int l15 = lane & 15;
    const int q = lane >> 4;

    // staging mapping (per thread, per chunk): A: 1 segment, B: 4 segments
    const int sr = lane >> 3;          // row within 8-row group
    const int s  = lane & 7;           // physical 16B segment
    const int g  = s ^ sr;             // logical k-segment held by this thread
    const int arow = w * 8 + sr;       // A stage row 0..63
    const int brow = w * 32 + sr;      // B stage row base (+ j*8, j=0..3)

    f32x4 acc[2][4] = {};
    float xrE[8], xrO[8];              // staged x (silu chunks), parity sets
    uint4 pkE, pkO;                    // gathered table rows (basis chunks)

    auto stage_b = [&](int kc, int buf) {
#pragma unroll
        for (int j = 0; j < 4; ++j) {
            const unsigned short* gp =
                Wc + (size_t)(brow + j * 8) * KDIM + kc * BK + g * 8;
            __builtin_amdgcn_global_load_lds((const AS1 void*)gp,
                (AS3 void*)(Bsb + buf * (256 * 64) + (w * 32 + j * 8) * 64), 16, 0, 0);
        }
    };
    auto load_x = [&](int c, float* xr, uint4& pk) {
        if (c < 4) {
            const float* xp = x + (size_t)(row0 + arow) * IN_F + c * 64 + g * 8;
            float4 a = *reinterpret_cast<const float4*>(xp);
            float4 b = *reinterpret_cast<const float4*>(xp + 4);
            xr[0] = a.x; xr[1] = a.y; xr[2] = a.z; xr[3] = a.w;
            xr[4] = b.x; xr[5] = b.y; xr[6] = b.z; xr[7] = b.w;
        } else {
            const int i0 = (c - 4) * 8 + g;
            float xx = x[(size_t)(row0 + arow) * IN_F + i0];
            float u = __builtin_fmaf(xx, 2.5f, 5.5f);   // (x - grid0)/h
            int ic = (int)floorf(u * (float)TBINS);
            ic = ic < -1 ? -1 : (ic > NTAB ? NTAB : ic); // guards are zero rows
            pk = tgt[ic + 1];
        }
    };
    auto write_a = [&](int c, int buf, const float* xr, const uint4& pk) {
        uint4 wv;
        if (c < 4) {
            wv.x = f2bf(silu_f(xr[0])) | (f2bf(silu_f(xr[1])) << 16);
            wv.y = f2bf(silu_f(xr[2])) | (f2bf(silu_f(xr[3])) << 16);
            wv.z = f2bf(silu_f(xr[4])) | (f2bf(silu_f(xr[5])) << 16);
            wv.w = f2bf(silu_f(xr[6])) | (f2bf(silu_f(xr[7])) << 16);
        } else {
            wv = pk;                   // table row is already positioned bf16x8
        }
        *reinterpret_cast<uint4*>(Asb + buf * (64 * 64) + arow * 64 + s * 8) = wv;
    };
    auto mfma_block = [&](int cur) {
        const unsigned short* Ac = Asb + cur * (64 * 64);
        const unsigned short* Bc = Bsb + cur * (256 * 64);
#pragma unroll
        for (int kk = 0; kk < BK; kk += 32) {
            bf16x8 af[2], bfv[4];
            const int g0 = (kk >> 3) + q;
#pragma unroll
            for (int mt = 0; mt < 2; ++mt) {
                int r = wm * 32 + mt * 16 + l15;
                af[mt] = *reinterpret_cast<const bf16x8*>(
                    Ac + r * 64 + ((g0 ^ (r & 7)) << 3));
            }
#pragma unroll
            for (int nt = 0; nt < 4; ++nt) {
                int r = wn * 64 + nt * 16 + l15;
                bfv[nt] = *reinterpret_cast<const bf16x8*>(
                    Bc + r * 64 + ((g0 ^ (r & 7)) << 3));
            }
            __builtin_amdgcn_s_setprio(1);
#pragma unroll
            for (int mt = 0; mt < 2; ++mt)
#pragma unroll
                for (int nt = 0; nt < 4; ++nt)
                    acc[mt][nt] = __builtin_amdgcn_mfma_f32_16x16x32_bf16(
                        af[mt], bfv[nt], acc[mt][nt], 0, 0, 0);
            __builtin_amdgcn_s_setprio(0);
        }
    };

    // prologue: chunk0 staged+written, chunk1 expansion in flight (set O)
    stage_b(0, 0);
    load_x(0, xrE, pkE);
    write_a(0, 0, xrE, pkE);
    load_x(1, xrO, pkO);
    __syncthreads();

    // steady state (unroll 2 for static parity-set naming):
    //   even kc: stage B(kc+1), issue expand(kc+2)->E, MFMA(cur), write A(kc+1)<-O
    //   odd  kc: stage B(kc+2), issue expand(kc+3)->O, MFMA(cur), write A(kc+2)<-E
    for (int kc = 0; kc < NCHUNK; kc += 2) {
        {
            if (kc + 1 < NCHUNK) stage_b(kc + 1, 1);
            if (kc + 2 < NCHUNK) load_x(kc + 2, xrE, pkE);
            mfma_block(0);
            if (kc + 1 < NCHUNK) write_a(kc + 1, 1, xrO, pkO);
            __syncthreads();
        }
        {
            if (kc + 2 < NCHUNK) stage_b(kc + 2, 0);
            if (kc + 3 < NCHUNK) load_x(kc + 3, xrO, pkO);
            mfma_block(1);
            if (kc + 2 < NCHUNK) write_a(kc + 2, 0, xrE, pkE);
            __syncthreads();
        }
    }

    // epilogue: C/D layout col = lane&15, row = (lane>>4)*4 + reg
#pragma unroll
    for (int mt = 0; mt < 2; ++mt) {
        int row = row0 + wm * 32 + mt * 16 + q * 4;
#pragma unroll
        for (int nt = 0; nt < 4; ++nt) {
            int col = wn * 64 + nt * 16 + l15;
#pragma unroll
            for (int r = 0; r < 4; ++r)
                out[(size_t)(row + r) * OUT_F + col] = acc[mt][nt][r];
        }
    }
}

extern "C" void kernel_launch(void* const* d_in, const int* in_sizes, int n_in,
                              void* d_out, int out_size, void* d_ws, size_t ws_size,
                              hipStream_t stream) {
    const float* x  = (const float*)d_in[0];
    const float* bw = (const float*)d_in[1];
    const float* sw = (const float*)d_in[2];
    const float* ss = (const float*)d_in[3];
    unsigned short* Wc = (unsigned short*)d_ws;                 // 1.18 MB
    uint4* tgt = (uint4*)((char*)d_ws + WC_BYTES);              // 90 KB table

    static bool attr_set = false;
    if (!attr_set) {
        (void)hipFuncSetAttribute(reinterpret_cast<const void*>(kan_fused),
                                  hipFuncAttributeMaxDynamicSharedMemorySize,
                                  LDS_BYTES);
        attr_set = true;
    }

    build_w<<<dim3(OUT_F), dim3(IN_F), 0, stream>>>(bw, sw, ss, Wc, tgt);

    const int B_ROWS = in_sizes[0] / IN_F;                      // 32768
    kan_fused<<<dim3(B_ROWS / 64), dim3(512), LDS_BYTES, stream>>>(
        x, Wc, tgt, (float*)d_out);
}